// Round 4
// baseline (170.494 us; speedup 1.0000x reference)
//
#include <hip/hip_runtime.h>
#include <hip/hip_fp16.h>

#define BATCH 2048

__device__ __forceinline__ float sigmoidf(float v) {
    return 1.0f / (1.0f + __expf(-v));
}

// ---------------------------------------------------------------------------
// W2 layout (f16, in d_ws): [q=0..19][t=0..1007] of float4 (8 halves).
//   t = c0*336 + o ; o = f*21 + g*7 + i  (c0 = m-chunk 0..2, m = c0*5 + m_l)
//   q: m_l = q>>2, rem0 = (q&3)*8 ; element rem = rem0+u (valid < 28, else 0)
//   src = tree_w[f*8820 + m*588 + g*196 + i*28 + rem]   (rem = j*4 + ki*2 + kj)
// ---------------------------------------------------------------------------
__global__ __launch_bounds__(256) void k_prep(
    const float* __restrict__ tree_w,
    float4* __restrict__ W2)            // 20160 float4 = 322,560 B
{
    int idx = blockIdx.x * 256 + threadIdx.x;   // one per (q,t)
    if (idx >= 20160) return;
    int q = idx / 1008;
    int t = idx - q * 1008;
    int c0 = t / 336;
    int o  = t - c0 * 336;
    int f  = o / 21;
    int gi = o - f * 21;
    int g  = gi / 7;
    int i  = gi - g * 7;
    int m  = c0 * 5 + (q >> 2);
    int rem0 = (q & 3) * 8;
    const float* src = tree_w + (size_t)f * 8820 + m * 588 + g * 196 + i * 28;
    union { float4 f4; __half h[8]; } u;
    #pragma unroll
    for (int uu = 0; uu < 8; uu++) {
        int rem = rem0 + uu;
        u.h[uu] = __float2half(rem < 28 ? src[rem] : 0.f);
    }
    W2[q * 1008 + t] = u.f4;
}

// ---------------------------------------------------------------------------
// Fully fused: conv5x5(grouped)+bias+sigmoid+maxpool2 + tree einsum+sigmoid + fc
// One image per block, 256 threads, 4 blocks/CU.
// LDS plan (35,392 B):
//   [0     .. 13056)  xs float[3*32*34]  (row stride 34 -> 8B-aligned rows)
//                      | after conv barrier: partials float[1008] @0,
//                      |                     ts float[336] @4096
//   [13056 .. 17556)  ws float[1125]
//   [17556 .. 17736)  bs float[45]
//   [17736 .. 35392)  ps __half[8828]  (tree-order pooled + 8 zero pad)
// ---------------------------------------------------------------------------
#define XS_OFF   0
#define WS_OFF   13056
#define BS_OFF   17556
#define PS_OFF   17736
#define PART_OFF 0
#define TS_OFF   4096
#define SMEM_SZ  35392

__global__ __launch_bounds__(256, 4) void fused_all(
    const float* __restrict__ x,       // [B][3][32][32]
    const float* __restrict__ conv_w,  // [45][25]
    const float* __restrict__ conv_b,  // [45]
    const float4* __restrict__ W2,     // prepped f16 tree weights
    const float* __restrict__ tree_b,  // [336]
    const float* __restrict__ fc_w,    // [10][336]
    const float* __restrict__ fc_b,    // [10]
    float* __restrict__ out)           // [B][10]
{
    __shared__ __align__(16) char smem[SMEM_SZ];
    float*  xs = (float*)(smem + XS_OFF);
    float*  ws = (float*)(smem + WS_OFF);
    float*  bs = (float*)(smem + BS_OFF);
    __half* ps = (__half*)(smem + PS_OFF);
    float*  partials = (float*)(smem + PART_OFF);
    float*  ts = (float*)(smem + TS_OFF);

    const int img = blockIdx.x;
    const int tid = threadIdx.x;

    // ---- stage x image (12 KB), conv weights, bias; zero ps pad ----
    const float4* xg = (const float4*)(x + (size_t)img * 3072);
    for (int idx = tid; idx < 768; idx += 256) {
        float4 v = xg[idx];
        int flat = idx * 4;
        int gch = flat >> 10;
        int rc = flat & 1023;
        int row = rc >> 5;
        int col = rc & 31;
        float* dst = xs + (gch * 32 + row) * 34 + col;
        dst[0] = v.x; dst[1] = v.y; dst[2] = v.z; dst[3] = v.w;
    }
    for (int idx = tid; idx < 1125; idx += 256) ws[idx] = conv_w[idx];
    if (tid < 45) bs[tid] = conv_b[tid];
    if (tid < 8) ps[8820 + tid] = __float2half(0.f);   // pad for tail reads
    __syncthreads();

    // ---- conv + pool + sigmoid ----
    // task = c*28 + half*14 + ph (ph in low bits); xs reads are 9x float2/row
    for (int task = tid; task < 1260; task += 256) {
        const int c    = task / 28;
        const int r28  = task - c * 28;
        const int half = r28 / 14;
        const int ph   = r28 - half * 14;
        const int g    = c / 15;

        const float* xbase = xs + (g * 32 + 2 * ph) * 34 + half * 14; // even word off
        const float* wc = ws + c * 25;

        float acc0[14], acc1[14];
        #pragma unroll
        for (int j = 0; j < 14; j++) { acc0[j] = 0.f; acc1[j] = 0.f; }

        #pragma unroll
        for (int r = 0; r < 6; r++) {
            float xr[18];
            const float2* row2 = (const float2*)(xbase + r * 34);
            #pragma unroll
            for (int q = 0; q < 9; q++) {
                float2 v = row2[q];
                xr[2 * q] = v.x; xr[2 * q + 1] = v.y;
            }
            if (r < 5) {
                #pragma unroll
                for (int kw = 0; kw < 5; kw++) {
                    float wv = wc[r * 5 + kw];
                    #pragma unroll
                    for (int j = 0; j < 14; j++) acc0[j] += xr[j + kw] * wv;
                }
            }
            if (r >= 1) {
                #pragma unroll
                for (int kw = 0; kw < 5; kw++) {
                    float wv = wc[(r - 1) * 5 + kw];
                    #pragma unroll
                    for (int j = 0; j < 14; j++) acc1[j] += xr[j + kw] * wv;
                }
            }
        }
        // pool pre-activation; store f16 tree order: c*196 + i*28 + j*4 + ki*2 + kj
        const float bias = bs[c];
        const int i_ = ph >> 1, ki = ph & 1;
        __half* pbase = ps + c * 196 + i_ * 28 + ki * 2;
        #pragma unroll
        for (int jj = 0; jj < 7; jj++) {
            const int pc = half * 7 + jj;
            const int j = pc >> 1, kj = pc & 1;
            float m = fmaxf(fmaxf(acc0[2 * jj], acc0[2 * jj + 1]),
                            fmaxf(acc1[2 * jj], acc1[2 * jj + 1]));
            pbase[j * 4 + kj] = __float2half(sigmoidf(m + bias));
        }
    }
    __syncthreads();

    // ---- tree einsum, 1008 balanced tasks; ps reads via 8B float2 ----
    for (int t = tid; t < 1008; t += 256) {
        const int c0 = t / 336;
        const int o  = t - c0 * 336;
        const int f  = o / 21;
        const int gi = o - f * 21;
        const int g  = gi / 7;
        const int i  = gi - g * 7;

        const __half* prow = ps + (g * 15 + c0 * 5) * 196 + i * 28;
        float acc = 0.f;
        #pragma unroll
        for (int q = 0; q < 20; q++) {
            union { float4 f4; __half2 h2[4]; } wu;
            wu.f4 = W2[q * 1008 + t];
            const int m_l = q >> 2;
            const int rem0 = (q & 3) * 8;
            const float2* pp2 = (const float2*)(prow + m_l * 196 + rem0); // 8B aligned
            union { float2 f2; __half2 h2[2]; } pu0, pu1;
            pu0.f2 = pp2[0];
            pu1.f2 = pp2[1];
            #pragma unroll
            for (int v = 0; v < 2; v++) {
                float2 pf = __half22float2(pu0.h2[v]);
                float2 wf = __half22float2(wu.h2[v]);
                acc = fmaf(pf.x, wf.x, acc);
                acc = fmaf(pf.y, wf.y, acc);
            }
            #pragma unroll
            for (int v = 0; v < 2; v++) {
                float2 pf = __half22float2(pu1.h2[v]);
                float2 wf = __half22float2(wu.h2[v + 2]);
                acc = fmaf(pf.x, wf.x, acc);
                acc = fmaf(pf.y, wf.y, acc);
            }
        }
        partials[t] = acc;
    }
    __syncthreads();

    // ---- finalize tree: sum 3 partials + bias, sigmoid ----
    for (int o = tid; o < 336; o += 256) {
        float v = partials[o] + partials[o + 336] + partials[o + 672] + tree_b[o];
        ts[o] = sigmoidf(v);
    }
    __syncthreads();

    // ---- fc 336 -> 10: wave per output, shuffle reduce ----
    const int wid  = tid >> 6;
    const int lane = tid & 63;
    for (int o = wid; o < 10; o += 4) {
        float partial = 0.f;
        for (int idx = lane; idx < 336; idx += 64)
            partial += ts[idx] * fc_w[o * 336 + idx];
        #pragma unroll
        for (int off = 32; off > 0; off >>= 1)
            partial += __shfl_down(partial, off);
        if (lane == 0)
            out[(size_t)img * 10 + o] = partial + fc_b[o];
    }
}

extern "C" void kernel_launch(void* const* d_in, const int* in_sizes, int n_in,
                              void* d_out, int out_size, void* d_ws, size_t ws_size,
                              hipStream_t stream) {
    const float* x      = (const float*)d_in[0];
    const float* conv_w = (const float*)d_in[1];
    const float* conv_b = (const float*)d_in[2];
    const float* tree_w = (const float*)d_in[3];
    const float* tree_b = (const float*)d_in[4];
    const float* fc_w   = (const float*)d_in[5];
    const float* fc_b   = (const float*)d_in[6];
    float* out = (float*)d_out;

    float4* W2 = (float4*)d_ws;   // 20160 float4 = 322,560 B

    k_prep<<<79, 256, 0, stream>>>(tree_w, W2);
    fused_all<<<BATCH, 256, 0, stream>>>(x, conv_w, conv_b, W2, tree_b,
                                         fc_w, fc_b, out);
}

// Round 5
// 157.315 us; speedup vs baseline: 1.0838x; 1.0838x over previous
//
#include <hip/hip_runtime.h>
#include <hip/hip_fp16.h>

#define BATCH 2048

typedef _Float16 f16x8 __attribute__((ext_vector_type(8)));
typedef _Float16 f16x2 __attribute__((ext_vector_type(2)));
typedef float f32x4 __attribute__((ext_vector_type(4)));

__device__ __forceinline__ float sigmoidf(float v) {
    return 1.0f / (1.0f + __expf(-v));
}

__device__ __forceinline__ f16x2 u2h(unsigned int u) {
    union { unsigned int u; f16x2 h; } c; c.u = u; return c.h;
}

__device__ __forceinline__ float fdot2f(f16x2 a, f16x2 b, float c) {
#if defined(__has_builtin) && __has_builtin(__builtin_amdgcn_fdot2)
    return __builtin_amdgcn_fdot2(a, b, c, false);
#else
    return c + (float)a[0] * (float)b[0] + (float)a[1] * (float)b[1];
#endif
}

// ---------------------------------------------------------------------------
// k_prep: repack weights into d_ws.
//  W3 (tree weights, f16): for (c0 0..2, gi 0..20, k4 0..34, fq 0..3, ff 0..3):
//    ushort4 at idx = (((c0*21+gi)*35 + k4)*4 + fq)*4 + ff
//    holds tree_w[f=fq*4+ff][m=c0*5+k4/7][g][i][(k4%7)*4 + u], u=0..3
//    -> tree task reads 32 B/lane contiguous per k4 step (perfect coalescing).
//  Wc (conv B-frags, f16): halves [g*512 + n*32 + k]; n=15 or k>=25 zero-pad.
// ---------------------------------------------------------------------------
__global__ __launch_bounds__(256) void k_prep(
    const float* __restrict__ tree_w,
    const float* __restrict__ conv_w,
    ushort* __restrict__ W3,      // 141120 halves = 282240 B
    ushort* __restrict__ Wc)      // 1536 halves = 3072 B
{
    int idx = blockIdx.x * 256 + threadIdx.x;
    if (idx < 35280) {
        int ff = idx & 3, fq = (idx >> 2) & 3;
        int t2 = idx >> 4;
        int k4 = t2 % 35, cg = t2 / 35;
        int c0 = cg / 21, gi = cg - c0 * 21;
        int g = gi / 7, i = gi - g * 7;
        int f = fq * 4 + ff;
        int m = c0 * 5 + k4 / 7;
        int rem4 = (k4 % 7) * 4;
        const float* src = tree_w + (size_t)f * 8820 + m * 588 + g * 196 + i * 28 + rem4;
        ushort4 o;
        o.x = __half_as_ushort(__float2half(src[0]));
        o.y = __half_as_ushort(__float2half(src[1]));
        o.z = __half_as_ushort(__float2half(src[2]));
        o.w = __half_as_ushort(__float2half(src[3]));
        ((ushort4*)W3)[idx] = o;
    } else if (idx < 36816) {
        int j = idx - 35280;
        int k = j & 31, nn = (j >> 5) & 15, g = j >> 9;
        float v = (nn < 15 && k < 25) ? conv_w[(g * 15 + nn) * 25 + k] : 0.f;
        Wc[j] = __half_as_ushort(__float2half(v));
    }
}

// ---------------------------------------------------------------------------
// fused_all: conv5x5(grouped, f16 MFMA) + bias + sigmoid + maxpool2
//            + tree einsum (fdot2) + sigmoid + fc.  One image per block.
// Position ordering for im2col: p = pb*4 + dr*2 + dc, pb = ph*14 + pw
//   (conv pos r = 2ph+dr, c = 2pw+dc) -> each MFMA tile row-quad = 1 pool block.
// im2col layout: chunk-major [q=0..3][p=0..783][8 halves] so A-frag read is
//   one ds_read_b128/lane at 16 B lane stride (m134's measured pattern).
// LDS: xs f16 [96][36] @0 (6912 B) | im2col @6912 (50176 B, aliased by
//   partials/ts after conv) | ps @57088 (17640 B, tree-order f16 pooled).
// 74.7 KB -> 2 blocks/CU.
// ---------------------------------------------------------------------------
#define XS_OFF 0
#define IM_OFF 6912
#define PS_OFF 57088
#define SMEM_SZ 74752

__global__ __launch_bounds__(256, 2) void fused_all(
    const float* __restrict__ x,       // [B][3][32][32]
    const float* __restrict__ conv_b,  // [45]
    const ushort* __restrict__ W3,     // prepped tree weights (f16)
    const ushort* __restrict__ Wc,     // prepped conv B-frags (f16)
    const float* __restrict__ tree_b,  // [336]
    const float* __restrict__ fc_w,    // [10][336]
    const float* __restrict__ fc_b,    // [10]
    float* __restrict__ out)           // [B][10]
{
    __shared__ __align__(16) char smem[SMEM_SZ];
    ushort* xs = (ushort*)(smem + XS_OFF);
    ushort* im = (ushort*)(smem + IM_OFF);
    ushort* ps = (ushort*)(smem + PS_OFF);
    float* partials = (float*)(smem + IM_OFF);          // 1008 f32, alias im
    float* ts       = (float*)(smem + IM_OFF + 4096);   // 336 f32, alias im

    const int img  = blockIdx.x;
    const int tid  = threadIdx.x;
    const int lane = tid & 63;
    const int n    = lane & 15;        // MFMA col role (channel) / A row (pos)
    const int q    = lane >> 4;        // k-chunk / D row-quad
    const int wave = tid >> 6;

    // ---- stage x -> f16 LDS, rows 0..95 (= g*32+r), stride 36 halves ----
    const float4* xg = (const float4*)(x + (size_t)img * 3072);
    #pragma unroll
    for (int it = 0; it < 3; it++) {
        int idx = tid + it * 256;
        float4 v = xg[idx];
        int flat = idx * 4;
        int row = flat >> 5, col = flat & 31;
        __half2 a = __float22half2_rn(make_float2(v.x, v.y));
        __half2 b = __float22half2_rn(make_float2(v.z, v.w));
        uint2 pk;
        pk.x = *(unsigned int*)&a;
        pk.y = *(unsigned int*)&b;
        *(uint2*)(xs + row * 36 + col) = pk;
    }

    // ---- preload conv B-fragments (B[k][n]: n=lane&15, k=q*8+j) + bias ----
    const f16x8* WcB = (const f16x8*)Wc;
    f16x8 Bf0 = WcB[0 * 64 + n * 4 + q];
    f16x8 Bf1 = WcB[1 * 64 + n * 4 + q];
    f16x8 Bf2 = WcB[2 * 64 + n * 4 + q];
    float bias0 = (n < 15) ? conv_b[n]      : 0.f;
    float bias1 = (n < 15) ? conv_b[15 + n] : 0.f;
    float bias2 = (n < 15) ? conv_b[30 + n] : 0.f;
    __syncthreads();

    for (int g = 0; g < 3; g++) {
        // ---- build im2col(g): 196 tasks = (r 0..27) x (cp 0..6), 4 pos each
        if (tid < 196) {
            int r = tid / 7, cp = tid - (tid / 7) * 7;
            int ph = r >> 1, dr = r & 1;
            ushort h[5][8];
            #pragma unroll
            for (int wr = 0; wr < 5; wr++) {
                const ushort* rp = xs + (g * 32 + r + wr) * 36 + cp * 4;
                uint2 a = *(const uint2*)rp;
                uint2 b = *(const uint2*)(rp + 4);
                h[wr][0] = (ushort)a.x; h[wr][1] = (ushort)(a.x >> 16);
                h[wr][2] = (ushort)a.y; h[wr][3] = (ushort)(a.y >> 16);
                h[wr][4] = (ushort)b.x; h[wr][5] = (ushort)(b.x >> 16);
                h[wr][6] = (ushort)b.y; h[wr][7] = (ushort)(b.y >> 16);
            }
            #pragma unroll
            for (int cc = 0; cc < 4; cc++) {
                int c = cp * 4 + cc;
                int pw = c >> 1, dc = c & 1;
                int p = (ph * 14 + pw) * 4 + dr * 2 + dc;
                union { ushort s[32]; uint4 q4[4]; } A;
                #pragma unroll
                for (int k = 0; k < 32; k++)
                    A.s[k] = (k < 25) ? h[k / 5][cc + (k % 5)] : (ushort)0;
                #pragma unroll
                for (int qq = 0; qq < 4; qq++)
                    *(uint4*)(im + (qq * 784 + p) * 8) = A.q4[qq];
            }
        }
        __syncthreads();

        // ---- MFMA: 49 tiles of 16 pos x 16 ch x 32 taps; pool+sigmoid+ps
        f16x8 Bf   = (g == 0) ? Bf0   : (g == 1 ? Bf1   : Bf2);
        float bias = (g == 0) ? bias0 : (g == 1 ? bias1 : bias2);
        for (int t = wave; t < 49; t += 4) {
            f16x8 Af = *(const f16x8*)(im + (q * 784 + t * 16 + n) * 8);
            f32x4 z = {0.f, 0.f, 0.f, 0.f};
            f32x4 d = __builtin_amdgcn_mfma_f32_16x16x32_f16(Af, Bf, z, 0, 0, 0);
            if (n < 15) {
                float mx = fmaxf(fmaxf(d[0], d[1]), fmaxf(d[2], d[3]));
                int pb = t * 4 + q;
                int ph2 = pb / 14, pw2 = pb - (pb / 14) * 14;
                int pi = (g * 15 + n) * 196 + (ph2 >> 1) * 28 + (pw2 >> 1) * 4
                       + (ph2 & 1) * 2 + (pw2 & 1);
                ps[pi] = __half_as_ushort(__float2half(sigmoidf(mx + bias)));
            }
        }
        __syncthreads();
    }

    // ---- tree: 252 tasks = (c0 0..2, gi 0..20, fq 0..3); 4 f each; one ps
    //      read (broadcast over fq) + 32 B coalesced W3 read per k4 step.
    if (tid < 252) {
        int fq  = tid & 3;
        int rem = tid >> 2;
        int gi = rem % 21, c0 = rem / 21;
        int g = gi / 7, i = gi - g * 7;
        const uint4* Wp = (const uint4*)W3;
        size_t wbase = ((size_t)((c0 * 21 + gi) * 35) * 4 + fq) * 2;
        const ushort* prow = ps + (g * 15 + c0 * 5) * 196 + i * 28;
        float a0 = 0.f, a1 = 0.f, a2 = 0.f, a3 = 0.f;
        #pragma unroll
        for (int ml = 0; ml < 5; ml++) {
            #pragma unroll
            for (int r4 = 0; r4 < 7; r4++) {
                uint2 pv = *(const uint2*)(prow + ml * 196 + r4 * 4);
                f16x2 p01 = u2h(pv.x), p23 = u2h(pv.y);
                int k4 = ml * 7 + r4;
                uint4 wa = Wp[wbase + (size_t)k4 * 8];
                uint4 wb = Wp[wbase + (size_t)k4 * 8 + 1];
                a0 = fdot2f(p01, u2h(wa.x), a0); a0 = fdot2f(p23, u2h(wa.y), a0);
                a1 = fdot2f(p01, u2h(wa.z), a1); a1 = fdot2f(p23, u2h(wa.w), a1);
                a2 = fdot2f(p01, u2h(wb.x), a2); a2 = fdot2f(p23, u2h(wb.y), a2);
                a3 = fdot2f(p01, u2h(wb.z), a3); a3 = fdot2f(p23, u2h(wb.w), a3);
            }
        }
        partials[c0 * 336 + (fq * 4 + 0) * 21 + gi] = a0;
        partials[c0 * 336 + (fq * 4 + 1) * 21 + gi] = a1;
        partials[c0 * 336 + (fq * 4 + 2) * 21 + gi] = a2;
        partials[c0 * 336 + (fq * 4 + 3) * 21 + gi] = a3;
    }
    __syncthreads();

    // ---- finalize tree: sum 3 m-chunks + bias, sigmoid ----
    for (int o = tid; o < 336; o += 256)
        ts[o] = sigmoidf(partials[o] + partials[o + 336] + partials[o + 672] + tree_b[o]);
    __syncthreads();

    // ---- fc 336 -> 10: wave per output, shuffle reduce ----
    for (int o = wave; o < 10; o += 4) {
        float partial = 0.f;
        for (int idx2 = lane; idx2 < 336; idx2 += 64)
            partial += ts[idx2] * fc_w[o * 336 + idx2];
        #pragma unroll
        for (int off = 32; off > 0; off >>= 1)
            partial += __shfl_down(partial, off);
        if (lane == 0)
            out[(size_t)img * 10 + o] = partial + fc_b[o];
    }
}

extern "C" void kernel_launch(void* const* d_in, const int* in_sizes, int n_in,
                              void* d_out, int out_size, void* d_ws, size_t ws_size,
                              hipStream_t stream) {
    const float* x      = (const float*)d_in[0];
    const float* conv_w = (const float*)d_in[1];
    const float* conv_b = (const float*)d_in[2];
    const float* tree_w = (const float*)d_in[3];
    const float* tree_b = (const float*)d_in[4];
    const float* fc_w   = (const float*)d_in[5];
    const float* fc_b   = (const float*)d_in[6];
    float* out = (float*)d_out;

    ushort* W3 = (ushort*)d_ws;                           // 282240 B
    ushort* Wc = (ushort*)((char*)d_ws + 282240);         // 3072 B

    k_prep<<<144, 256, 0, stream>>>(tree_w, conv_w, W3, Wc);
    fused_all<<<BATCH, 256, 0, stream>>>(x, conv_b, W3, Wc, tree_b,
                                         fc_w, fc_b, out);
}

// Round 6
// 142.617 us; speedup vs baseline: 1.1955x; 1.1031x over previous
//
#include <hip/hip_runtime.h>
#include <hip/hip_fp16.h>

#define BATCH 2048

typedef _Float16 f16x8 __attribute__((ext_vector_type(8)));
typedef float f32x4 __attribute__((ext_vector_type(4)));

__device__ __forceinline__ float sigmoidf(float v) {
    return 1.0f / (1.0f + __expf(-v));
}

// ---------------------------------------------------------------------------
// Workspace layout (bytes):
//   [0        .. 301056)   W3B  tree B-frags f16: [gi 21][c 14][lane 64][8]
//                          value = W[k=c*32+(lane>>4)*8+u][f=lane&15], k<420
//                          k = mm*28 + r ; r = j*4+ki*2+kj ; mm = m index in g
//   [301056   .. 304128)   Wc   conv B-frags f16: [g][n*32+k]
//   [304128   .. 36430848) ps   f16 pooled: [img][ch 45][196 tree-order]
//   [36430848 .. 39183360) ts   f32 tree out: [img][336]
// ---------------------------------------------------------------------------
#define WS_W3B 0
#define WS_WC  301056
#define WS_PS  304128
#define WS_TS  36430848

__global__ __launch_bounds__(256) void k_prep(
    const float* __restrict__ tree_w,
    const float* __restrict__ conv_w,
    ushort* __restrict__ W3B,
    ushort* __restrict__ Wc)
{
    int idx = blockIdx.x * 256 + threadIdx.x;
    if (idx < 18816) {                       // 21*14*64 uint4
        int gi = idx / 896;
        int rem = idx - gi * 896;
        int c = rem >> 6, lane = rem & 63;
        int n = lane & 15, q = lane >> 4;
        int g = gi / 7, i = gi - g * 7;
        ushort h[8];
        #pragma unroll
        for (int u = 0; u < 8; u++) {
            int k = c * 32 + q * 8 + u;
            float v = 0.f;
            if (k < 420) {
                int mm = k / 28, r = k - mm * 28;
                v = tree_w[(size_t)n * 8820 + mm * 588 + g * 196 + i * 28 + r];
            }
            h[u] = __half_as_ushort(__float2half(v));
        }
        *(uint4*)(W3B + (size_t)idx * 8) = *(uint4*)h;
    } else if (idx < 18816 + 192) {          // Wc: 1536 halves as 192 uint4
        int j8 = idx - 18816;
        ushort h[8];
        #pragma unroll
        for (int u = 0; u < 8; u++) {
            int flat = j8 * 8 + u;
            int k = flat & 31, nn = (flat >> 5) & 15, g = flat >> 9;
            float v = (nn < 15 && k < 25) ? conv_w[(g * 15 + nn) * 25 + k] : 0.f;
            h[u] = __half_as_ushort(__float2half(v));
        }
        *(uint4*)(Wc + (size_t)j8 * 8) = *(uint4*)h;
    }
}

// ---------------------------------------------------------------------------
// kA: conv5x5 + bias + sigmoid + maxpool2 for ONE (img, g).  6144 blocks.
// LDS: xs f16 [32][36] (2304 B) + im2col [q 4][p 784][8 halves] (50176 B)
//   = 52480 B -> 3 blocks/CU.  Only 2 barriers.
// Position order p = pb*4 + dr*2 + dc (pb = pool block) so each MFMA lane's
// 4 acc regs = one 2x2 pool window.
// ---------------------------------------------------------------------------
__global__ __launch_bounds__(256, 3) void kA_conv(
    const float* __restrict__ x,       // [B][3][32][32]
    const float* __restrict__ conv_b,  // [45]
    const ushort* __restrict__ Wc,     // conv B-frags
    ushort* __restrict__ ps)           // f16 [img][45][196]
{
    __shared__ __align__(16) char smem[52480];
    ushort* xs = (ushort*)smem;            // [32][36]
    ushort* im = (ushort*)(smem + 2304);   // [4][784][8]

    const int blk  = blockIdx.x;
    const int img  = blk / 3;
    const int g    = blk - img * 3;
    const int tid  = threadIdx.x;
    const int lane = tid & 63;
    const int n    = lane & 15;
    const int q    = lane >> 4;
    const int wave = tid >> 6;

    // ---- stage x channel (4 KB f32 -> f16 LDS rows stride 36) ----
    {
        float4 v = ((const float4*)(x + (size_t)img * 3072 + g * 1024))[tid];
        int row = tid >> 3, col = (tid & 7) * 4;
        __half2 a = __float22half2_rn(make_float2(v.x, v.y));
        __half2 b = __float22half2_rn(make_float2(v.z, v.w));
        uint2 pk;
        pk.x = *(unsigned int*)&a;
        pk.y = *(unsigned int*)&b;
        *(uint2*)(xs + row * 36 + col) = pk;
    }

    // ---- preload conv B-frag + bias ----
    f16x8 Bf = ((const f16x8*)Wc)[g * 64 + n * 4 + q];
    float bias = (n < 15) ? conv_b[g * 15 + n] : 0.f;
    __syncthreads();

    // ---- build im2col: 196 tasks = (r 0..27, cp 0..6), 4 positions each ----
    if (tid < 196) {
        int r = tid / 7, cp = tid - (tid / 7) * 7;
        int ph = r >> 1, dr = r & 1;
        ushort h[5][8];
        #pragma unroll
        for (int wr = 0; wr < 5; wr++) {
            const ushort* rp = xs + (r + wr) * 36 + cp * 4;
            uint2 a = *(const uint2*)rp;
            uint2 b = *(const uint2*)(rp + 4);
            h[wr][0] = (ushort)a.x; h[wr][1] = (ushort)(a.x >> 16);
            h[wr][2] = (ushort)a.y; h[wr][3] = (ushort)(a.y >> 16);
            h[wr][4] = (ushort)b.x; h[wr][5] = (ushort)(b.x >> 16);
            h[wr][6] = (ushort)b.y; h[wr][7] = (ushort)(b.y >> 16);
        }
        #pragma unroll
        for (int cc = 0; cc < 4; cc++) {
            int c = cp * 4 + cc;
            int pw = c >> 1, dc = c & 1;
            int p = (ph * 14 + pw) * 4 + dr * 2 + dc;
            union { ushort s[32]; uint4 q4[4]; } A;
            #pragma unroll
            for (int k = 0; k < 32; k++)
                A.s[k] = (k < 25) ? h[k / 5][cc + (k % 5)] : (ushort)0;
            #pragma unroll
            for (int qq = 0; qq < 4; qq++)
                *(uint4*)(im + (qq * 784 + p) * 8) = A.q4[qq];
        }
    }
    __syncthreads();

    // ---- 49 MFMA tiles; pool + sigmoid; scatter f16 stores to ps ----
    ushort* pso = ps + (size_t)img * 8820 + (g * 15 + n) * 196;
    for (int t = wave; t < 49; t += 4) {
        f16x8 Af = *(const f16x8*)(im + (q * 784 + t * 16 + n) * 8);
        f32x4 z = {0.f, 0.f, 0.f, 0.f};
        f32x4 d = __builtin_amdgcn_mfma_f32_16x16x32_f16(Af, Bf, z, 0, 0, 0);
        if (n < 15) {
            float mx = fmaxf(fmaxf(d[0], d[1]), fmaxf(d[2], d[3]));
            int pb = t * 4 + q;
            int ph2 = pb / 14, pw2 = pb - (pb / 14) * 14;
            int pi = (ph2 >> 1) * 28 + (pw2 >> 1) * 4 + (ph2 & 1) * 2 + (pw2 & 1);
            pso[pi] = __half_as_ushort(__float2half(sigmoidf(mx + bias)));
        }
    }
}

// ---------------------------------------------------------------------------
// kB: tree einsum as MFMA GEMM over images.  Block = 128 thr (2 waves),
// one (gi, 32-image tile).  Grid (64, 21) = 1344 blocks.
// A = ps slices [img 32][k 456 pad] f16 in LDS (29184 B -> 5 blocks/CU);
// B = weights in 14 f16x8 VGPR frags (preloaded, shared via L2).
// Wave w computes the 16-img tile w with 14 chained MFMAs (K=448).
// ---------------------------------------------------------------------------
__global__ __launch_bounds__(128, 5) void kB_tree(
    const ushort* __restrict__ ps,     // f16 [img][45][196]
    const ushort* __restrict__ W3B,    // tree B-frags
    const float* __restrict__ tree_b,  // [336]
    float* __restrict__ ts)            // f32 [img][336]
{
    __shared__ __align__(16) ushort im[32 * 456];   // 29184 B

    const int btile = blockIdx.x;
    const int gi    = blockIdx.y;
    const int g = gi / 7, i = gi - g * 7;
    const int img0 = btile * 32;
    const int tid  = threadIdx.x;
    const int lane = tid & 63;
    const int n    = lane & 15;
    const int q    = lane >> 4;
    const int wave = tid >> 6;

    // ---- stage A: 480 granules of 28 halves (56 B) ----
    for (int t = tid; t < 480; t += 128) {
        int img = t / 15, mm = t - (t / 15) * 15;
        const uint2* src = (const uint2*)(ps + (size_t)(img0 + img) * 8820
                                          + (g * 15 + mm) * 196 + i * 28);
        uint2* dst = (uint2*)(im + img * 456 + mm * 28);
        #pragma unroll
        for (int u = 0; u < 7; u++) dst[u] = src[u];
    }
    // zero-fill k = 420..455
    for (int t = tid; t < 288; t += 128) {
        int img = t / 9, c4 = t - (t / 9) * 9;
        *(uint2*)(im + img * 456 + 420 + c4 * 4) = make_uint2(0u, 0u);
    }

    // ---- preload 14 B-frags (coalesced 16 B/lane, L2-shared) ----
    const f16x8* Wbase = (const f16x8*)W3B + (size_t)gi * 896;
    f16x8 B[14];
    #pragma unroll
    for (int c = 0; c < 14; c++) B[c] = Wbase[c * 64 + lane];
    __syncthreads();

    // ---- 14 chained MFMAs: D[img16 x f16] ----
    f32x4 D = {0.f, 0.f, 0.f, 0.f};
    const ushort* arow = im + (wave * 16 + n) * 456;
    #pragma unroll
    for (int c = 0; c < 14; c++) {
        f16x8 Af = *(const f16x8*)(arow + c * 32 + q * 8);
        D = __builtin_amdgcn_mfma_f32_16x16x32_f16(Af, B[c], D, 0, 0, 0);
    }

    // ---- epilogue: bias + sigmoid, scatter to ts ----
    float bias = tree_b[n * 21 + gi];
    #pragma unroll
    for (int r = 0; r < 4; r++) {
        int img = img0 + wave * 16 + q * 4 + r;
        ts[(size_t)img * 336 + n * 21 + gi] = sigmoidf(D[r] + bias);
    }
}

// ---------------------------------------------------------------------------
// kC: fc 336 -> 10.  thread = (img, o16) with o16<10 active. 128 blocks.
// ---------------------------------------------------------------------------
__global__ __launch_bounds__(256) void kC_fc(
    const float* __restrict__ ts,      // [2048][336]
    const float* __restrict__ fc_w,    // [10][336]
    const float* __restrict__ fc_b,    // [10]
    float* __restrict__ out)           // [2048][10]
{
    int gid = blockIdx.x * 256 + threadIdx.x;
    int img = gid >> 4;
    int o = gid & 15;
    if (o >= 10) return;
    const float4* tr = (const float4*)(ts + (size_t)img * 336);
    const float4* wr = (const float4*)(fc_w + o * 336);
    float acc = fc_b[o];
    #pragma unroll 4
    for (int j = 0; j < 84; j++) {
        float4 a = tr[j], b = wr[j];
        acc += a.x * b.x + a.y * b.y + a.z * b.z + a.w * b.w;
    }
    out[(size_t)img * 10 + o] = acc;
}

extern "C" void kernel_launch(void* const* d_in, const int* in_sizes, int n_in,
                              void* d_out, int out_size, void* d_ws, size_t ws_size,
                              hipStream_t stream) {
    const float* x      = (const float*)d_in[0];
    const float* conv_w = (const float*)d_in[1];
    const float* conv_b = (const float*)d_in[2];
    const float* tree_w = (const float*)d_in[3];
    const float* tree_b = (const float*)d_in[4];
    const float* fc_w   = (const float*)d_in[5];
    const float* fc_b   = (const float*)d_in[6];
    float* out = (float*)d_out;

    ushort* W3B = (ushort*)((char*)d_ws + WS_W3B);
    ushort* Wc  = (ushort*)((char*)d_ws + WS_WC);
    ushort* ps  = (ushort*)((char*)d_ws + WS_PS);
    float*  ts  = (float*)((char*)d_ws + WS_TS);

    k_prep<<<75, 256, 0, stream>>>(tree_w, conv_w, W3B, Wc);
    kA_conv<<<BATCH * 3, 256, 0, stream>>>(x, conv_b, Wc, ps);
    kB_tree<<<dim3(64, 21), 128, 0, stream>>>(ps, W3B, tree_b, ts);
    kC_fc<<<128, 256, 0, stream>>>(ts, fc_w, fc_b, out);
}

// Round 8
// 133.931 us; speedup vs baseline: 1.2730x; 1.0649x over previous
//
#include <hip/hip_runtime.h>
#include <hip/hip_fp16.h>

#define BATCH 2048

typedef _Float16 f16x8 __attribute__((ext_vector_type(8)));
typedef float f32x4 __attribute__((ext_vector_type(4)));

__device__ __forceinline__ float sigmoidf(float v) {
    return 1.0f / (1.0f + __expf(-v));
}

// ---------------------------------------------------------------------------
// Workspace layout (bytes):
//   [0        .. 301056)   W3B  tree B-frags f16 [gi 21][c 14][lane 64][8h]
//   [301056   .. 307200)   Wc   conv B-frags f16 [g 3][mf 2][n 16][k 32]
//                          mf0: k=wr*8+wc -> w[n][wr*5+wc] (wc<5), rows 0..3
//                          mf1: k<5 -> w[n][20+k] (row 4), else 0
//   [307200   .. 308768)   LUT1 ushort[784]: p -> xs-copies half-offset
//   [308768   .. 309160)   LUT2 ushort[196]: pb -> i*32 + ridx
//   [309248   .. 36780032) ps2  f16 pooled [gi 21][img 2048][424]
//                          (element n*28+r, r=j*4+ki*2+kj; halves 420..423 = 0
//                           pad so kB can stage whole rows as uint4: 424=53*8)
//   [36780032 .. 38156288) ts   f16 [img][336]
// ---------------------------------------------------------------------------
#define WS_W3B  0
#define WS_WC   301056
#define WS_LUT1 307200
#define WS_LUT2 308768
#define WS_PS   309248
#define WS_TS   36780032
#define PS_ROW  424
#define PS_IMG_STRIDE ((size_t)2048 * PS_ROW)

__global__ __launch_bounds__(256) void k_prep(
    const float* __restrict__ tree_w,
    const float* __restrict__ conv_w,
    ushort* __restrict__ W3B,
    ushort* __restrict__ Wc,
    ushort* __restrict__ lut1,
    ushort* __restrict__ lut2)
{
    int idx = blockIdx.x * 256 + threadIdx.x;
    if (idx < 18816) {                       // W3B: 21*14*64 uint4
        int gi = idx / 896;
        int rem = idx - gi * 896;
        int c = rem >> 6, lane = rem & 63;
        int n = lane & 15, q = lane >> 4;
        int g = gi / 7, i = gi - g * 7;
        ushort h[8];
        #pragma unroll
        for (int u = 0; u < 8; u++) {
            int k = c * 32 + q * 8 + u;
            float v = 0.f;
            if (k < 420) {
                int mm = k / 28, r = k - mm * 28;
                v = tree_w[(size_t)n * 8820 + mm * 588 + g * 196 + i * 28 + r];
            }
            h[u] = __half_as_ushort(__float2half(v));
        }
        *(uint4*)(W3B + (size_t)idx * 8) = *(uint4*)h;
    } else if (idx < 21888) {                // Wc: 3072 halves
        int j = idx - 18816;
        int k = j & 31, n = (j >> 5) & 15, mf = (j >> 9) & 1, g = j >> 10;
        float v = 0.f;
        if (n < 15) {
            if (mf == 0) {
                int wr = k >> 3, wc = k & 7;
                if (wc < 5) v = conv_w[(g * 15 + n) * 25 + wr * 5 + wc];
            } else {
                if (k < 5) v = conv_w[(g * 15 + n) * 25 + 20 + k];
            }
        }
        Wc[j] = __half_as_ushort(__float2half(v));
    } else if (idx < 22672) {                // LUT1: 784
        int p = idx - 21888;
        int pb = p >> 2, dr = (p >> 1) & 1, dc = p & 1;
        int ph = pb / 14, pw = pb - ph * 14;
        int r = 2 * ph + dr, c = 2 * pw + dc;
        int s = c & 3;
        lut1[p] = (ushort)(s * 1164 + r * 36 + (c - s));
    } else if (idx < 22868) {                // LUT2: 196
        int pb = idx - 22672;
        int ph = pb / 14, pw = pb - ph * 14;
        lut2[pb] = (ushort)((ph >> 1) * 32 + (pw >> 1) * 4 + (ph & 1) * 2 + (pw & 1));
    }
}

// ---------------------------------------------------------------------------
// kA: conv5x5 + bias + sigmoid + maxpool2 for one (img, g).  6144 blocks.
// No im2col: A-frags read directly from 4 shift-replicated f16 copies of the
// 32x36 channel image (tap order k = wr*8+wc, rows 0-3; 2nd MFMA = row 4).
// LDS: 4 copies x 1164 halves + LUT1 784 + LUT2 196 = 11,280 B.
// ---------------------------------------------------------------------------
__global__ __launch_bounds__(256, 4) void kA_conv(
    const float* __restrict__ x,       // [B][3][32][32]
    const float* __restrict__ conv_b,  // [45]
    const ushort* __restrict__ Wc,
    const ushort* __restrict__ lut1,
    const ushort* __restrict__ lut2,
    ushort* __restrict__ ps2)          // [21][2048][424] f16
{
    __shared__ __align__(16) ushort sm[5640];
    ushort* xsc = sm;                  // 4 copies, stride 1164 halves
    ushort* l1  = sm + 4656;           // 784
    ushort* l2  = sm + 5440;           // 196

    const int blk  = blockIdx.x;
    const int img  = blk / 3;
    const int g    = blk - img * 3;
    const int tid  = threadIdx.x;
    const int lane = tid & 63;
    const int n    = lane & 15;
    const int q    = lane >> 4;
    const int wave = tid >> 6;

    // ---- phase 1: x channel -> f16 copy0 (rows stride 36), pads, LUTs ----
    {
        float4 v = ((const float4*)(x + (size_t)img * 3072 + g * 1024))[tid];
        int row = tid >> 3, col = (tid & 7) * 4;
        __half2 a = __float22half2_rn(make_float2(v.x, v.y));
        __half2 b = __float22half2_rn(make_float2(v.z, v.w));
        uint2 pk;
        pk.x = *(unsigned int*)&a;
        pk.y = *(unsigned int*)&b;
        *(uint2*)(xsc + row * 36 + col) = pk;
    }
    if (tid < 32) *(uint2*)(xsc + tid * 36 + 32) = make_uint2(0u, 0u);
    for (int t = tid; t < 980; t += 256) {
        if (t < 784) l1[t] = lut1[t];
        else         l2[t - 784] = lut2[t - 784];
    }
    // zero ps2 pad halves 420..423 for this (g, i=0..6, img)
    if (tid < 7) {
        ushort* pp = ps2 + ((size_t)(g * 7 + tid) * 2048 + img) * PS_ROW + 420;
        *(uint2*)pp = make_uint2(0u, 0u);
    }
    __syncthreads();

    // ---- phase 2: build shifted copies s=1..3 (LDS->LDS, aligned b64) ----
    for (int t = tid; t < 864; t += 256) {
        int s = t / 288 + 1;
        int rem = t - (s - 1) * 288;
        int row = rem / 9, g4 = rem - row * 9;
        ushort* dst = xsc + s * 1164 + row * 36 + g4 * 4;
        if (g4 == 8) { *(uint2*)dst = make_uint2(0u, 0u); continue; }
        uint2 lo = *(const uint2*)(xsc + row * 36 + g4 * 4);
        uint2 hi = *(const uint2*)(xsc + row * 36 + g4 * 4 + 4);
        unsigned int w0 = lo.x, w1 = lo.y, w2 = hi.x, w3 = hi.y;
        unsigned int o0, o1;
        if (s == 1)      { o0 = (w0 >> 16) | (w1 << 16); o1 = (w1 >> 16) | (w2 << 16); }
        else if (s == 2) { o0 = w1;                      o1 = w2; }
        else             { o0 = (w1 >> 16) | (w2 << 16); o1 = (w2 >> 16) | (w3 << 16); }
        *(uint2*)dst = make_uint2(o0, o1);
    }

    // ---- B-frags + bias (global loads overlap phase2) ----
    const f16x8* WcB = (const f16x8*)Wc;
    f16x8 B1 = WcB[((g * 2 + 0) * 16 + n) * 4 + q];
    f16x8 B2 = WcB[((g * 2 + 1) * 16 + n) * 4 + q];
    float bias = (n < 15) ? conv_b[g * 15 + n] : 0.f;
    __syncthreads();

    // ---- 49 tiles: 2 MFMAs each, direct A-reads, pool+sigmoid+store ----
    ushort* psg = ps2 + (size_t)(g * 7) * PS_IMG_STRIDE + (size_t)img * PS_ROW;
    for (int t = wave; t < 49; t += 4) {
        int off = l1[t * 16 + n];
        const ushort* basep = xsc + off;
        union { struct { uint2 a, b; } u; f16x8 v; } A1, A2;
        A1.u.a = *(const uint2*)(basep + q * 36);
        A1.u.b = *(const uint2*)(basep + q * 36 + 4);
        A2.u.a = *(const uint2*)(basep + 144);          // row r+4
        A2.u.b = *(const uint2*)(basep + 148);
        f32x4 d = {0.f, 0.f, 0.f, 0.f};
        d = __builtin_amdgcn_mfma_f32_16x16x32_f16(A1.v, B1, d, 0, 0, 0);
        d = __builtin_amdgcn_mfma_f32_16x16x32_f16(A2.v, B2, d, 0, 0, 0);
        if (n < 15) {
            float mx = fmaxf(fmaxf(d[0], d[1]), fmaxf(d[2], d[3]));
            int lv = l2[t * 4 + q];
            int i = lv >> 5, ridx = lv & 31;
            psg[(size_t)i * PS_IMG_STRIDE + n * 28 + ridx] =
                __half_as_ushort(__float2half(sigmoidf(mx + bias)));
        }
    }
}

// ---------------------------------------------------------------------------
// kB: tree einsum as MFMA GEMM over images.  Block = 128 thr, one
// (gi, 32-img tile).  Grid (64, 21).  Staging: 53 uint4 granules per image
// (424 = 53*8 halves, never straddles an image row), fully coalesced.
// ---------------------------------------------------------------------------
__global__ __launch_bounds__(128, 5) void kB_tree(
    const ushort* __restrict__ ps2,    // [21][2048][424] f16
    const ushort* __restrict__ W3B,
    const float* __restrict__ tree_b,  // [336]
    ushort* __restrict__ ts)           // f16 [img][336]
{
    __shared__ __align__(16) ushort im[32 * 456];

    const int btile = blockIdx.x;
    const int gi    = blockIdx.y;
    const int img0  = btile * 32;
    const int tid   = threadIdx.x;
    const int lane  = tid & 63;
    const int n     = lane & 15;
    const int q     = lane >> 4;
    const int wave  = tid >> 6;

    // ---- stage 32 images x 53 uint4 (halves 0..423 incl. zero pad) ----
    const uint4* src = (const uint4*)(ps2 + ((size_t)gi * 2048 + img0) * PS_ROW);
    for (int t = tid; t < 1696; t += 128) {
        int img = t / 53;
        int off8 = t - img * 53;
        uint4 v = src[t];
        *(uint4*)(im + img * 456 + off8 * 8) = v;
    }
    // zero k-space 424..455 (k=420..447 is read by c=13; weights there are 0)
    for (int t = tid; t < 256; t += 128) {
        int img = t >> 3, o = t & 7;
        *(uint2*)(im + img * 456 + 424 + o * 4) = make_uint2(0u, 0u);
    }

    // ---- preload 14 B-frags (16 B/lane coalesced, L2-shared) ----
    const f16x8* Wbase = (const f16x8*)W3B + (size_t)gi * 896;
    f16x8 B[14];
    #pragma unroll
    for (int c = 0; c < 14; c++) B[c] = Wbase[c * 64 + lane];
    __syncthreads();

    // ---- 14 chained MFMAs: D[img16 x f16] ----
    f32x4 D = {0.f, 0.f, 0.f, 0.f};
    const ushort* arow = im + (wave * 16 + n) * 456;
    #pragma unroll
    for (int c = 0; c < 14; c++) {
        f16x8 Af = *(const f16x8*)(arow + c * 32 + q * 8);
        D = __builtin_amdgcn_mfma_f32_16x16x32_f16(Af, B[c], D, 0, 0, 0);
    }

    // ---- bias + sigmoid -> ts (f16) ----
    float bias = tree_b[n * 21 + gi];
    #pragma unroll
    for (int r = 0; r < 4; r++) {
        int img = img0 + wave * 16 + q * 4 + r;
        ts[(size_t)img * 336 + n * 21 + gi] =
            __half_as_ushort(__float2half(sigmoidf(D[r] + bias)));
    }
}

// ---------------------------------------------------------------------------
// kC: fc 336 -> 10, one thread per (img, o).
// ---------------------------------------------------------------------------
__global__ __launch_bounds__(256) void kC_fc(
    const ushort* __restrict__ ts,     // f16 [2048][336]
    const float* __restrict__ fc_w,    // [10][336]
    const float* __restrict__ fc_b,    // [10]
    float* __restrict__ out)           // [2048][10]
{
    int gid = blockIdx.x * 256 + threadIdx.x;
    if (gid >= BATCH * 10) return;
    int img = gid / 10, o = gid - (gid / 10) * 10;
    const __half2* tr = (const __half2*)(ts + (size_t)img * 336);
    const float2* wr = (const float2*)(fc_w + o * 336);
    float acc = fc_b[o];
    #pragma unroll 4
    for (int j = 0; j < 168; j++) {
        float2 t2 = __half22float2(tr[j]);
        float2 w2 = wr[j];
        acc = fmaf(t2.x, w2.x, acc);
        acc = fmaf(t2.y, w2.y, acc);
    }
    out[(size_t)img * 10 + o] = acc;
}

extern "C" void kernel_launch(void* const* d_in, const int* in_sizes, int n_in,
                              void* d_out, int out_size, void* d_ws, size_t ws_size,
                              hipStream_t stream) {
    const float* x      = (const float*)d_in[0];
    const float* conv_w = (const float*)d_in[1];
    const float* conv_b = (const float*)d_in[2];
    const float* tree_w = (const float*)d_in[3];
    const float* tree_b = (const float*)d_in[4];
    const float* fc_w   = (const float*)d_in[5];
    const float* fc_b   = (const float*)d_in[6];
    float* out = (float*)d_out;

    ushort* W3B  = (ushort*)((char*)d_ws + WS_W3B);
    ushort* Wc   = (ushort*)((char*)d_ws + WS_WC);
    ushort* lut1 = (ushort*)((char*)d_ws + WS_LUT1);
    ushort* lut2 = (ushort*)((char*)d_ws + WS_LUT2);
    ushort* ps2  = (ushort*)((char*)d_ws + WS_PS);
    ushort* ts   = (ushort*)((char*)d_ws + WS_TS);

    k_prep<<<90, 256, 0, stream>>>(tree_w, conv_w, W3B, Wc, lut1, lut2);
    kA_conv<<<BATCH * 3, 256, 0, stream>>>(x, conv_b, Wc, lut1, lut2, ps2);
    kB_tree<<<dim3(64, 21), 128, 0, stream>>>(ps2, W3B, tree_b, ts);
    kC_fc<<<80, 256, 0, stream>>>(ts, fc_w, fc_b, out);
}

// Round 10
// 133.868 us; speedup vs baseline: 1.2736x; 1.0005x over previous
//
#include <hip/hip_runtime.h>
#include <hip/hip_fp16.h>

#define BATCH 2048

typedef _Float16 f16x8 __attribute__((ext_vector_type(8)));
typedef float f32x4 __attribute__((ext_vector_type(4)));

__device__ __forceinline__ float sigmoidf(float v) {
    return 1.0f / (1.0f + __expf(-v));
}

// ---------------------------------------------------------------------------
// Workspace layout (bytes):
//   [0      .. 301056)   W3B  tree B-frags f16 [gi 21][c 14][lane 64][8h]
//   [301056 .. 307200)   Wc   conv B-frags f16 [g 3][mf 2][n 16][k 32]
//                        mf0: k=wr*8+wc -> w[n][wr*5+wc] (wc<5), rows 0..3
//                        mf1: k<5 -> w[n][20+k] (row 4), else 0
//   [307200 .. 328704)   FCW  f32 [gi 21][o 16][f 16]  (o>=10 -> 0)
//   [328704 .. 36799488) ps2  f16 pooled [gi 21][img 2048][424]
//                        (el n*28+r, r=j*4+ki*2+kj; 420..423 zero pad so a
//                         424-half row = 53 whole uint4 granules)
// ---------------------------------------------------------------------------
#define WS_W3B  0
#define WS_WC   301056
#define WS_FCW  307200
#define WS_PS   328704
#define PS_ROW  424
#define PS_IMG_STRIDE ((size_t)2048 * PS_ROW)

__global__ __launch_bounds__(256) void k_prep(
    const float* __restrict__ tree_w,
    const float* __restrict__ conv_w,
    const float* __restrict__ fc_w,
    ushort* __restrict__ W3B,
    ushort* __restrict__ Wc,
    float* __restrict__ FCW)
{
    int idx = blockIdx.x * 256 + threadIdx.x;
    if (idx < 18816) {                       // W3B: 21*14*64 uint4
        int gi = idx / 896;
        int rem = idx - gi * 896;
        int c = rem >> 6, lane = rem & 63;
        int n = lane & 15, q = lane >> 4;
        int g = gi / 7, i = gi - g * 7;
        ushort h[8];
        #pragma unroll
        for (int u = 0; u < 8; u++) {
            int k = c * 32 + q * 8 + u;
            float v = 0.f;
            if (k < 420) {
                int mm = k / 28, r = k - mm * 28;
                v = tree_w[(size_t)n * 8820 + mm * 588 + g * 196 + i * 28 + r];
            }
            h[u] = __half_as_ushort(__float2half(v));
        }
        *(uint4*)(W3B + (size_t)idx * 8) = *(uint4*)h;
    } else if (idx < 21888) {                // Wc: 3072 halves
        int j = idx - 18816;
        int k = j & 31, n = (j >> 5) & 15, mf = (j >> 9) & 1, g = j >> 10;
        float v = 0.f;
        if (n < 15) {
            if (mf == 0) {
                int wr = k >> 3, wc = k & 7;
                if (wc < 5) v = conv_w[(g * 15 + n) * 25 + wr * 5 + wc];
            } else {
                if (k < 5) v = conv_w[(g * 15 + n) * 25 + 20 + k];
            }
        }
        Wc[j] = __half_as_ushort(__float2half(v));
    } else if (idx < 27264) {                // FCW: 21*16*16 f32
        int j = idx - 21888;
        int f = j & 15, o = (j >> 4) & 15, gi = j >> 8;
        FCW[j] = (o < 10) ? fc_w[o * 336 + f * 21 + gi] : 0.f;
    }
}

// ---------------------------------------------------------------------------
// kA: conv5x5 + bias + sigmoid + maxpool2, one block per IMAGE (all 3 g).
// A-frags read directly from 4 shift-replicated f16 copies per channel
// (tap order k = wr*8+wc rows 0..3; 2nd MFMA = row 4).  LUT-free.
// NOTE: A-read coords decode from p = t*16+n (A row), but the STORE decodes
// from pbs = t*4+q (D row-quad = pool block) — these are different!
// LDS: 3 g x 4 copies x 1164 halves = 27,936 B -> 4 blocks/CU.
// ---------------------------------------------------------------------------
__global__ __launch_bounds__(256, 4) void kA_conv(
    const float* __restrict__ x,       // [B][3][32][32]
    const float* __restrict__ conv_b,  // [45]
    const ushort* __restrict__ Wc,
    ushort* __restrict__ ps2)          // [21][2048][424] f16
{
    __shared__ __align__(16) ushort xsc[3 * 4656];

    const int img  = blockIdx.x;
    const int tid  = threadIdx.x;
    const int lane = tid & 63;
    const int n    = lane & 15;
    const int q    = lane >> 4;
    const int wave = tid >> 6;

    // ---- phase 1: whole image -> f16 copy0 per g (rows stride 36) ----
    const float4* xg = (const float4*)(x + (size_t)img * 3072);
    #pragma unroll
    for (int it = 0; it < 3; it++) {
        int idx = tid + it * 256;
        float4 v = xg[idx];
        int flat = idx * 4;
        int row = flat >> 5;           // 0..95 (g*32 + r)
        int g = row >> 5, r = row & 31;
        int col = flat & 31;
        __half2 a = __float22half2_rn(make_float2(v.x, v.y));
        __half2 b = __float22half2_rn(make_float2(v.z, v.w));
        uint2 pk;
        pk.x = *(unsigned int*)&a;
        pk.y = *(unsigned int*)&b;
        *(uint2*)(xsc + g * 4656 + r * 36 + col) = pk;
    }
    if (tid < 96) {                    // zero cols 32..35 of copy0
        int g = tid >> 5, r = tid & 31;
        *(uint2*)(xsc + g * 4656 + r * 36 + 32) = make_uint2(0u, 0u);
    }
    if (tid < 21) {                    // zero ps2 pad halves 420..423
        ushort* pp = ps2 + ((size_t)tid * 2048 + img) * PS_ROW + 420;
        *(uint2*)pp = make_uint2(0u, 0u);
    }
    __syncthreads();

    // ---- phase 2: shifted copies s=1..3 for each g (LDS->LDS b64) ----
    for (int t = tid; t < 2592; t += 256) {
        int gg = t / 864;
        int rem = t - gg * 864;
        int s = rem / 288 + 1;
        int rem2 = rem - (s - 1) * 288;
        int row = rem2 / 9, g4 = rem2 - row * 9;
        ushort* base = xsc + gg * 4656;
        ushort* dst = base + s * 1164 + row * 36 + g4 * 4;
        if (g4 == 8) { *(uint2*)dst = make_uint2(0u, 0u); continue; }
        uint2 lo = *(const uint2*)(base + row * 36 + g4 * 4);
        uint2 hi = *(const uint2*)(base + row * 36 + g4 * 4 + 4);
        unsigned int w0 = lo.x, w1 = lo.y, w2 = hi.x, w3 = hi.y;
        unsigned int o0, o1;
        if (s == 1)      { o0 = (w0 >> 16) | (w1 << 16); o1 = (w1 >> 16) | (w2 << 16); }
        else if (s == 2) { o0 = w1;                      o1 = w2; }
        else             { o0 = (w1 >> 16) | (w2 << 16); o1 = (w2 >> 16) | (w3 << 16); }
        *(uint2*)dst = make_uint2(o0, o1);
    }

    // ---- B-frags + biases (global L2 loads overlap phase 2) ----
    const f16x8* WcB = (const f16x8*)Wc;
    f16x8 B1g[3], B2g[3];
    float biasg[3];
    #pragma unroll
    for (int g = 0; g < 3; g++) {
        B1g[g] = WcB[((g * 2 + 0) * 16 + n) * 4 + q];
        B2g[g] = WcB[((g * 2 + 1) * 16 + n) * 4 + q];
        biasg[g] = (n < 15) ? conv_b[g * 15 + n] : 0.f;
    }
    __syncthreads();

    // ---- g-major tile loop: 49 tiles per g, 2 MFMAs each ----
    #pragma unroll
    for (int g = 0; g < 3; g++) {
        const ushort* xb = xsc + g * 4656;
        const f16x8 B1 = B1g[g], B2 = B2g[g];
        const float bias = biasg[g];
        ushort* psg = ps2 + (size_t)(g * 7) * PS_IMG_STRIDE + (size_t)img * PS_ROW;
        for (int t = wave; t < 49; t += 4) {
            // A-read coords from p = t*16 + n
            int p = t * 16 + n;
            int pb = p >> 2;
            int ph = pb / 14, pw = pb - ph * 14;
            int dr = (p >> 1) & 1, dc = p & 1;
            int r = 2 * ph + dr, c = 2 * pw + dc;
            int s = c & 3;
            const ushort* basep = xb + s * 1164 + r * 36 + (c - s);
            union { struct { uint2 a, b; } u; f16x8 v; } A1, A2;
            A1.u.a = *(const uint2*)(basep + q * 36);
            A1.u.b = *(const uint2*)(basep + q * 36 + 4);
            A2.u.a = *(const uint2*)(basep + 144);       // row r+4
            A2.u.b = *(const uint2*)(basep + 148);
            f32x4 d = {0.f, 0.f, 0.f, 0.f};
            d = __builtin_amdgcn_mfma_f32_16x16x32_f16(A1.v, B1, d, 0, 0, 0);
            d = __builtin_amdgcn_mfma_f32_16x16x32_f16(A2.v, B2, d, 0, 0, 0);
            if (n < 15) {
                float mx = fmaxf(fmaxf(d[0], d[1]), fmaxf(d[2], d[3]));
                // STORE coords from pool block pbs = t*4 + q (D row-quad)
                int pbs = t * 4 + q;
                int phs = pbs / 14, pws = pbs - phs * 14;
                int i = phs >> 1;
                int ridx = (pws >> 1) * 4 + (phs & 1) * 2 + (pws & 1);
                psg[(size_t)i * PS_IMG_STRIDE + n * 28 + ridx] =
                    __half_as_ushort(__float2half(sigmoidf(mx + bias)));
            }
        }
    }
}

// ---------------------------------------------------------------------------
// kBC: tree einsum (MFMA GEMM over images) + sigmoid + PARTIAL FC with
// atomic accumulation into out.  Block = 128 thr, one (gi, 32-img tile).
// Grid (64, 21).  LDS: im 29,184 B + ts 1,024 B.
// ---------------------------------------------------------------------------
__global__ __launch_bounds__(128, 3) void kBC_tree_fc(
    const ushort* __restrict__ ps2,    // [21][2048][424] f16
    const ushort* __restrict__ W3B,
    const float* __restrict__ tree_b,  // [336]
    const float* __restrict__ FCW,     // [21][16][16] f32
    const float* __restrict__ fc_b,    // [10]
    float* __restrict__ out)           // [2048][10] (pre-zeroed)
{
    __shared__ __align__(16) ushort im[32 * 456];
    __shared__ __align__(16) ushort tsl[32 * 16];

    const int btile = blockIdx.x;
    const int gi    = blockIdx.y;
    const int img0  = btile * 32;
    const int tid   = threadIdx.x;
    const int lane  = tid & 63;
    const int n     = lane & 15;
    const int q     = lane >> 4;
    const int wave  = tid >> 6;

    // ---- stage 32 images x 53 uint4 (halves 0..423 incl. zero pad) ----
    const uint4* src = (const uint4*)(ps2 + ((size_t)gi * 2048 + img0) * PS_ROW);
    for (int t = tid; t < 1696; t += 128) {
        int img = t / 53;
        int off8 = t - img * 53;
        uint4 v = src[t];
        *(uint4*)(im + img * 456 + off8 * 8) = v;
    }
    for (int t = tid; t < 256; t += 128) {   // zero k-space 424..455
        int img = t >> 3, o = t & 7;
        *(uint2*)(im + img * 456 + 424 + o * 4) = make_uint2(0u, 0u);
    }

    // ---- preload 14 B-frags (16 B/lane coalesced, L2-shared) ----
    const f16x8* Wbase = (const f16x8*)W3B + (size_t)gi * 896;
    f16x8 B[14];
    #pragma unroll
    for (int c = 0; c < 14; c++) B[c] = Wbase[c * 64 + lane];
    __syncthreads();

    // ---- 14 chained MFMAs: D[img16 x f16] ----
    f32x4 D = {0.f, 0.f, 0.f, 0.f};
    const ushort* arow = im + (wave * 16 + n) * 456;
    #pragma unroll
    for (int c = 0; c < 14; c++) {
        f16x8 Af = *(const f16x8*)(arow + c * 32 + q * 8);
        D = __builtin_amdgcn_mfma_f32_16x16x32_f16(Af, B[c], D, 0, 0, 0);
    }

    // ---- bias + sigmoid -> ts tile in LDS ([imgLocal 32][f 16] f16) ----
    float bias = tree_b[n * 21 + gi];
    #pragma unroll
    for (int r = 0; r < 4; r++) {
        int imgL = wave * 16 + q * 4 + r;
        tsl[imgL * 16 + n] = __half_as_ushort(__float2half(sigmoidf(D[r] + bias)));
    }
    __syncthreads();

    // ---- partial FC: 320 tasks (img, o); 16-feat dot; atomic add ----
    const float4* Wfc = (const float4*)(FCW + gi * 256);
    for (int t = tid; t < 320; t += 128) {
        int img = t / 10, o = t - (t / 10) * 10;
        const uint4* tp = (const uint4*)(tsl + img * 16);
        uint4 t0 = tp[0], t1 = tp[1];
        const __half2* h = (const __half2*)&t0;
        const __half2* h2 = (const __half2*)&t1;
        float4 w0 = Wfc[o * 4], w1 = Wfc[o * 4 + 1];
        float4 w2 = Wfc[o * 4 + 2], w3 = Wfc[o * 4 + 3];
        float acc = (gi == 0) ? fc_b[o] : 0.f;
        float2 p;
        p = __half22float2(h[0]);  acc = fmaf(p.x, w0.x, acc); acc = fmaf(p.y, w0.y, acc);
        p = __half22float2(h[1]);  acc = fmaf(p.x, w0.z, acc); acc = fmaf(p.y, w0.w, acc);
        p = __half22float2(h[2]);  acc = fmaf(p.x, w1.x, acc); acc = fmaf(p.y, w1.y, acc);
        p = __half22float2(h[3]);  acc = fmaf(p.x, w1.z, acc); acc = fmaf(p.y, w1.w, acc);
        p = __half22float2(h2[0]); acc = fmaf(p.x, w2.x, acc); acc = fmaf(p.y, w2.y, acc);
        p = __half22float2(h2[1]); acc = fmaf(p.x, w2.z, acc); acc = fmaf(p.y, w2.w, acc);
        p = __half22float2(h2[2]); acc = fmaf(p.x, w3.x, acc); acc = fmaf(p.y, w3.y, acc);
        p = __half22float2(h2[3]); acc = fmaf(p.x, w3.z, acc); acc = fmaf(p.y, w3.w, acc);
#if defined(__HIP_PLATFORM_AMD__)
        unsafeAtomicAdd(out + (size_t)(img0 + img) * 10 + o, acc);
#else
        atomicAdd(out + (size_t)(img0 + img) * 10 + o, acc);
#endif
    }
}

extern "C" void kernel_launch(void* const* d_in, const int* in_sizes, int n_in,
                              void* d_out, int out_size, void* d_ws, size_t ws_size,
                              hipStream_t stream) {
    const float* x      = (const float*)d_in[0];
    const float* conv_w = (const float*)d_in[1];
    const float* conv_b = (const float*)d_in[2];
    const float* tree_w = (const float*)d_in[3];
    const float* tree_b = (const float*)d_in[4];
    const float* fc_w   = (const float*)d_in[5];
    const float* fc_b   = (const float*)d_in[6];
    float* out = (float*)d_out;

    ushort* W3B = (ushort*)((char*)d_ws + WS_W3B);
    ushort* Wc  = (ushort*)((char*)d_ws + WS_WC);
    float*  FCW = (float*)((char*)d_ws + WS_FCW);
    ushort* ps2 = (ushort*)((char*)d_ws + WS_PS);

    hipMemsetAsync(out, 0, (size_t)BATCH * 10 * sizeof(float), stream);
    k_prep<<<107, 256, 0, stream>>>(tree_w, conv_w, fc_w, W3B, Wc, FCW);
    kA_conv<<<BATCH, 256, 0, stream>>>(x, conv_b, Wc, ps2);
    kBC_tree_fc<<<dim3(64, 21), 128, 0, stream>>>(ps2, W3B, tree_b, FCW, fc_b, out);
}

// Round 11
// 120.892 us; speedup vs baseline: 1.4103x; 1.1073x over previous
//
#include <hip/hip_runtime.h>
#include <hip/hip_fp16.h>

#define BATCH 2048
#define NPREP 95   // prep blocks prefixed to kA's grid

typedef _Float16 f16x8 __attribute__((ext_vector_type(8)));
typedef float f32x4 __attribute__((ext_vector_type(4)));

__device__ __forceinline__ float sigmoidf(float v) {
    return 1.0f / (1.0f + __expf(-v));
}

// ---------------------------------------------------------------------------
// Workspace layout (bytes):
//   [0      .. 301056)   W3B  tree B-frags f16 [gi 21][c 14][lane 64][8h]
//                        value for k = c*32 + (lane>>4)*8 + u, f = lane&15,
//                        k decoded in ps3 order: tt=k>>6, qq=(k>>4)&3, nn=k&15
//   [301056 .. 322560)   FCW  f32 [gi 21][o 16][f 16]  (o>=10 -> 0)
//   [322560 .. 38857728) ps3  f16 pooled [gi 21][img 2048][448]
//                        half-offset o = tt*64 + q*16 + n  (pb=(7i+tt)*4+q,
//                        channel n within g; n==15 stored as 0.0)
//                        448 = 14 exact K=32 MFMA chunks; no kB zero-fill.
// ---------------------------------------------------------------------------
#define WS_W3B  0
#define WS_FCW  301056
#define WS_PS   322560
#define PS_G_STRIDE (7u * 2048u * 448u)   // halves per g

// ---------------------------------------------------------------------------
// kA: blocks [0, NPREP) = weight prep (W3B + FCW, consumed only by kBC);
//     blocks [NPREP, NPREP+2048) = conv5x5+bias+sigmoid+maxpool2, one IMAGE.
// Conv A-frags read directly from 4 shift-replicated f16 copies per channel
// (taps k=wr*8+wc rows 0..3; 2nd MFMA = row 4, B2 nonzero only k<5).
// A-offsets and store-offsets precomputed ONCE per wave (hoisted over g);
// stores are one coalesced 128 B global_store per tile (lane-linear layout).
// LDS: 3 g x 4656 halves = 27,936 B -> 4 blocks/CU.
// ---------------------------------------------------------------------------
__global__ __launch_bounds__(256, 4) void kA_conv_prep(
    const float* __restrict__ x,       // [B][3][32][32]
    const float* __restrict__ conv_w,  // [45][25]
    const float* __restrict__ conv_b,  // [45]
    const float* __restrict__ tree_w,  // [16][15][3][7][7][2][2]
    const float* __restrict__ fc_w,    // [10][336]
    ushort* __restrict__ W3B,
    float* __restrict__ FCW,
    ushort* __restrict__ ps3)          // [21][2048][448] f16
{
    __shared__ __align__(16) ushort xsc[3 * 4656];
    const int tid = threadIdx.x;

    if (blockIdx.x < NPREP) {
        // ================= prep path (no barriers, no LDS use) =============
        int pidx = blockIdx.x * 256 + tid;
        if (pidx < 18816) {                     // W3B: 21*14*64 uint4
            int gi = pidx / 896;
            int rem = pidx - gi * 896;
            int c = rem >> 6, lane2 = rem & 63;
            int f = lane2 & 15, qq = lane2 >> 4;
            int g = gi / 7, i = gi - g * 7;
            ushort h[8];
            #pragma unroll
            for (int u = 0; u < 8; u++) {
                int k = c * 32 + qq * 8 + u;    // 0..447
                int tt = k >> 6;
                int q2 = (k >> 4) & 3;
                int nn = k & 15;
                int u27 = tt * 4 + q2;          // 0..27
                int ki = u27 / 14;
                int pw = u27 - ki * 14;
                int j = pw >> 1, kj = pw & 1;
                float v = 0.f;
                if (nn < 15)
                    v = tree_w[(size_t)f * 8820 + nn * 588 + g * 196 + i * 28
                               + j * 4 + ki * 2 + kj];
                h[u] = __half_as_ushort(__float2half(v));
            }
            *(uint4*)(W3B + (size_t)pidx * 8) = *(uint4*)h;
        } else if (pidx < 24192) {              // FCW: 21*16*16 f32
            int j = pidx - 18816;
            int f = j & 15, o = (j >> 4) & 15, gi = j >> 8;
            FCW[j] = (o < 10) ? fc_w[o * 336 + f * 21 + gi] : 0.f;
        }
        return;
    }

    // ==================== conv path ========================================
    const int img  = blockIdx.x - NPREP;
    const int lane = tid & 63;
    const int n    = lane & 15;
    const int q    = lane >> 4;
    const int wave = tid >> 6;

    // ---- phase 1: whole image -> f16 copy0 per g (rows stride 36) ----
    const float4* xg = (const float4*)(x + (size_t)img * 3072);
    #pragma unroll
    for (int it = 0; it < 3; it++) {
        int idx = tid + it * 256;
        float4 v = xg[idx];
        int flat = idx * 4;
        int row = flat >> 5;           // 0..95 (g*32 + r)
        int g = row >> 5, r = row & 31;
        int col = flat & 31;
        __half2 a = __float22half2_rn(make_float2(v.x, v.y));
        __half2 b = __float22half2_rn(make_float2(v.z, v.w));
        uint2 pk;
        pk.x = *(unsigned int*)&a;
        pk.y = *(unsigned int*)&b;
        *(uint2*)(xsc + g * 4656 + r * 36 + col) = pk;
    }
    if (tid < 96) {                    // zero cols 32..35 of copy0
        int g = tid >> 5, r = tid & 31;
        *(uint2*)(xsc + g * 4656 + r * 36 + 32) = make_uint2(0u, 0u);
    }

    // ---- B-frags + biases direct from conv_w (L2-hot, overlaps phase 2) ----
    f16x8 B1g[3], B2g[3];
    float biasg[3];
    #pragma unroll
    for (int g = 0; g < 3; g++) {
        f16x8 b1 = {0, 0, 0, 0, 0, 0, 0, 0};
        f16x8 b2 = {0, 0, 0, 0, 0, 0, 0, 0};
        float bb = 0.f;
        if (n < 15) {
            const float* wrow = conv_w + (g * 15 + n) * 25;
            #pragma unroll
            for (int u = 0; u < 5; u++) b1[u] = (_Float16)wrow[q * 5 + u];
            if (q == 0) {
                #pragma unroll
                for (int u = 0; u < 5; u++) b2[u] = (_Float16)wrow[20 + u];
            }
            bb = conv_b[g * 15 + n];
        }
        B1g[g] = b1; B2g[g] = b2; biasg[g] = bb;
    }
    __syncthreads();

    // ---- phase 2: shifted copies s=1..3 for each g (LDS->LDS b64) ----
    for (int t = tid; t < 2592; t += 256) {
        int gg = t / 864;
        int rem = t - gg * 864;
        int s = rem / 288 + 1;
        int rem2 = rem - (s - 1) * 288;
        int row = rem2 / 9, g4 = rem2 - row * 9;
        ushort* base = xsc + gg * 4656;
        ushort* dst = base + s * 1164 + row * 36 + g4 * 4;
        if (g4 == 8) { *(uint2*)dst = make_uint2(0u, 0u); continue; }
        uint2 lo = *(const uint2*)(base + row * 36 + g4 * 4);
        uint2 hi = *(const uint2*)(base + row * 36 + g4 * 4 + 4);
        unsigned int w0 = lo.x, w1 = lo.y, w2 = hi.x, w3 = hi.y;
        unsigned int o0, o1;
        if (s == 1)      { o0 = (w0 >> 16) | (w1 << 16); o1 = (w1 >> 16) | (w2 << 16); }
        else if (s == 2) { o0 = w1;                      o1 = w2; }
        else             { o0 = (w1 >> 16) | (w2 << 16); o1 = (w2 >> 16) | (w3 << 16); }
        *(uint2*)dst = make_uint2(o0, o1);
    }

    // ---- hoisted per-wave tile offsets (g-independent) ----
    const int dr = (n >> 1) & 1, dc = n & 1, n4 = n >> 2;
    const int a2c = 144 - q * 36;      // A1 base -> row r+4 (uniform result)
    int aoff[13], sv[13];
    #pragma unroll
    for (int it = 0; it < 13; it++) {
        int t = wave + it * 4;
        if (t < 49) {
            int pb = t * 4 + n4;
            int ph = pb / 14, pw = pb - ph * 14;
            int r = 2 * ph + dr, c = 2 * pw + dc;
            int s = c & 3;
            aoff[it] = s * 1164 + (r + q) * 36 + (c - s);   // A1 (row r+q)
            int i = t / 7, tt = t - i * 7;
            sv[it] = (i * 2048 + img) * 448 + tt * 64 + lane;
        } else { aoff[it] = 0; sv[it] = 0; }
    }
    __syncthreads();

    // ---- g-major tile loop: 2 MFMAs per tile, 1 coalesced store ----
    #pragma unroll
    for (int g = 0; g < 3; g++) {
        const ushort* xb = xsc + g * 4656;
        const f16x8 B1 = B1g[g], B2 = B2g[g];
        const float bias = biasg[g];
        ushort* psg = ps3 + (size_t)g * PS_G_STRIDE;
        #pragma unroll
        for (int it = 0; it < 13; it++) {
            int t = wave + it * 4;
            if (t < 49) {
                const ushort* pA = xb + aoff[it];
                union { struct { uint2 a, b; } u; f16x8 v; } A1, A2;
                A1.u.a = *(const uint2*)pA;
                A1.u.b = *(const uint2*)(pA + 4);
                A2.u.a = *(const uint2*)(pA + a2c);        // row r+4 (all q)
                A2.u.b = *(const uint2*)(pA + a2c + 4);
                f32x4 d = {0.f, 0.f, 0.f, 0.f};
                d = __builtin_amdgcn_mfma_f32_16x16x32_f16(A1.v, B1, d, 0, 0, 0);
                d = __builtin_amdgcn_mfma_f32_16x16x32_f16(A2.v, B2, d, 0, 0, 0);
                float mx = fmaxf(fmaxf(d[0], d[1]), fmaxf(d[2], d[3]));
                float val = (n < 15) ? sigmoidf(mx + bias) : 0.f;
                psg[sv[it]] = __half_as_ushort(__float2half(val));
            }
        }
    }
}

// ---------------------------------------------------------------------------
// kBC: tree einsum (MFMA GEMM over images) + sigmoid + partial FC with
// atomic accumulation into out.  Block = 128 thr, one (gi, 32-img tile).
// Grid (64, 21).  Staging: 56 exact uint4 per image, fully coalesced;
// K = 448 = 14 exact chunks, no zero-fill.
// ---------------------------------------------------------------------------
__global__ __launch_bounds__(128, 3) void kBC_tree_fc(
    const ushort* __restrict__ ps3,    // [21][2048][448] f16
    const ushort* __restrict__ W3B,
    const float* __restrict__ tree_b,  // [336]
    const float* __restrict__ FCW,     // [21][16][16] f32
    const float* __restrict__ fc_b,    // [10]
    float* __restrict__ out)           // [2048][10] (pre-zeroed)
{
    __shared__ __align__(16) ushort im[32 * 456];
    __shared__ __align__(16) ushort tsl[32 * 16];

    const int btile = blockIdx.x;
    const int gi    = blockIdx.y;
    const int img0  = btile * 32;
    const int tid   = threadIdx.x;
    const int lane  = tid & 63;
    const int n     = lane & 15;
    const int q     = lane >> 4;
    const int wave  = tid >> 6;

    // ---- stage 32 images x 56 uint4 (whole 448-half rows) ----
    const uint4* src = (const uint4*)(ps3 + ((size_t)gi * 2048 + img0) * 448);
    #pragma unroll
    for (int it = 0; it < 14; it++) {          // 1792 = 14 * 128 exactly
        int t = tid + it * 128;
        int img = t / 56;
        int o = t - img * 56;
        *(uint4*)(im + img * 456 + o * 8) = src[t];
    }

    // ---- preload 14 B-frags (16 B/lane coalesced, L2-shared) ----
    const f16x8* Wbase = (const f16x8*)W3B + (size_t)gi * 896;
    f16x8 B[14];
    #pragma unroll
    for (int c = 0; c < 14; c++) B[c] = Wbase[c * 64 + lane];
    __syncthreads();

    // ---- 14 chained MFMAs: D[img16 x f16] ----
    f32x4 D = {0.f, 0.f, 0.f, 0.f};
    const ushort* arow = im + (wave * 16 + n) * 456;
    #pragma unroll
    for (int c = 0; c < 14; c++) {
        f16x8 Af = *(const f16x8*)(arow + c * 32 + q * 8);
        D = __builtin_amdgcn_mfma_f32_16x16x32_f16(Af, B[c], D, 0, 0, 0);
    }

    // ---- bias + sigmoid -> ts tile in LDS ([imgLocal 32][f 16] f16) ----
    float bias = tree_b[n * 21 + gi];
    #pragma unroll
    for (int r = 0; r < 4; r++) {
        int imgL = wave * 16 + q * 4 + r;
        tsl[imgL * 16 + n] = __half_as_ushort(__float2half(sigmoidf(D[r] + bias)));
    }
    __syncthreads();

    // ---- partial FC: 320 tasks (img, o); 16-feat dot; atomic add ----
    const float4* Wfc = (const float4*)(FCW + gi * 256);
    for (int t = tid; t < 320; t += 128) {
        int img = t / 10, o = t - (t / 10) * 10;
        const uint4* tp = (const uint4*)(tsl + img * 16);
        uint4 t0 = tp[0], t1 = tp[1];
        const __half2* h = (const __half2*)&t0;
        const __half2* h2 = (const __half2*)&t1;
        float4 w0 = Wfc[o * 4], w1 = Wfc[o * 4 + 1];
        float4 w2 = Wfc[o * 4 + 2], w3 = Wfc[o * 4 + 3];
        float acc = (gi == 0) ? fc_b[o] : 0.f;
        float2 p;
        p = __half22float2(h[0]);  acc = fmaf(p.x, w0.x, acc); acc = fmaf(p.y, w0.y, acc);
        p = __half22float2(h[1]);  acc = fmaf(p.x, w0.z, acc); acc = fmaf(p.y, w0.w, acc);
        p = __half22float2(h[2]);  acc = fmaf(p.x, w1.x, acc); acc = fmaf(p.y, w1.y, acc);
        p = __half22float2(h[3]);  acc = fmaf(p.x, w1.z, acc); acc = fmaf(p.y, w1.w, acc);
        p = __half22float2(h2[0]); acc = fmaf(p.x, w2.x, acc); acc = fmaf(p.y, w2.y, acc);
        p = __half22float2(h2[1]); acc = fmaf(p.x, w2.z, acc); acc = fmaf(p.y, w2.w, acc);
        p = __half22float2(h2[2]); acc = fmaf(p.x, w3.x, acc); acc = fmaf(p.y, w3.y, acc);
        p = __half22float2(h2[3]); acc = fmaf(p.x, w3.z, acc); acc = fmaf(p.y, w3.w, acc);
#if defined(__HIP_PLATFORM_AMD__)
        unsafeAtomicAdd(out + (size_t)(img0 + img) * 10 + o, acc);
#else
        atomicAdd(out + (size_t)(img0 + img) * 10 + o, acc);
#endif
    }
}

extern "C" void kernel_launch(void* const* d_in, const int* in_sizes, int n_in,
                              void* d_out, int out_size, void* d_ws, size_t ws_size,
                              hipStream_t stream) {
    const float* x      = (const float*)d_in[0];
    const float* conv_w = (const float*)d_in[1];
    const float* conv_b = (const float*)d_in[2];
    const float* tree_w = (const float*)d_in[3];
    const float* tree_b = (const float*)d_in[4];
    const float* fc_w   = (const float*)d_in[5];
    const float* fc_b   = (const float*)d_in[6];
    float* out = (float*)d_out;

    ushort* W3B = (ushort*)((char*)d_ws + WS_W3B);
    float*  FCW = (float*)((char*)d_ws + WS_FCW);
    ushort* ps3 = (ushort*)((char*)d_ws + WS_PS);

    hipMemsetAsync(out, 0, (size_t)BATCH * 10 * sizeof(float), stream);
    kA_conv_prep<<<BATCH + NPREP, 256, 0, stream>>>(x, conv_w, conv_b, tree_w,
                                                    fc_w, W3B, FCW, ps3);
    kBC_tree_fc<<<dim3(64, 21), 128, 0, stream>>>(ps3, W3B, tree_b, FCW, fc_b, out);
}